// Round 11
// baseline (198.101 us; speedup 1.0000x reference)
//
#include <hip/hip_runtime.h>

#define FDIM 32
#define LOG2E 1.44269504088896340f

typedef _Float16 half8  __attribute__((ext_vector_type(8)));
typedef float    f32x4  __attribute__((ext_vector_type(4)));
typedef float    f32x16 __attribute__((ext_vector_type(16)));

// base-2 sigmoid: z' = z*log2e pre-scaled; sigma = 1/(1+2^-z')
__device__ __forceinline__ float fsig2(float z2) {
    return __builtin_amdgcn_rcpf(1.0f + __builtin_amdgcn_exp2f(-z2));
}
// true sigmoid (prep only)
__device__ __forceinline__ float fsig(float z) {
    return __builtin_amdgcn_rcpf(1.0f + __builtin_amdgcn_exp2f(-z * LOG2E));
}

// 32x32 MFMA C-layout: col = lane&31 (sample), row32 = (r&3)+8*(r>>2)+4*hb,
// hb = lane>>5, r = C-reg 0..15. Global A-row rho = 32*b + row32 (block b of 8).
// Row permutation: lane (sample, hb), block b, reg r  ->  tree slot so that each
// lane's 16 regs = one complete depth-4 subtree J = 8*hb+b (15 nodes) + 1 path node.
//   r 0..7   -> L7: slot 128+8J+r   (leaf pair t=r)
//   r 8..11  -> L6: slot 64+4J+(r-8)
//   r 12..13 -> L5: slot 32+2J+(r-12)
//   r 14     -> L4: slot 16+J
//   r 15     -> path node: hb=0: {1,2,4,5,8,9,10,11}[b]; hb=1: {1,3,6,7,12,13,14,15}[b]
__device__ __forceinline__ int slot_of(int b, int hb, int r) {
    int J = 8 * hb + b;
    if (r < 8)   return 128 + 8 * J + r;
    if (r < 12)  return 64 + 4 * J + (r - 8);
    if (r < 14)  return 32 + 2 * J + (r - 12);
    if (r == 14) return 16 + J;
    if (b == 0)  return 1;                    // root (duplicated for both hb)
    if (b == 1)  return 2 + hb;
    if (b < 4)   return 4 + 2 * hb + (b - 2);
    return 8 + 4 * hb + (b - 4);
}

// Prep (4 blocks x 256 thr; 4 threads per row, 8 k's each):
// Wh[rho][32] = relu(fi[slot-1])*log2e f16 (permuted), negc[b*32+hb*16+r] =
// -c*log2e, Dtab[16J+2t] = {cls0-cls1, cls1} for leaf pair t of subtree J.
__global__ void dtree_prep(const float* __restrict__ fi, const float* __restrict__ fs,
                           const float* __restrict__ cls,
                           _Float16* __restrict__ Wh, float* __restrict__ negc,
                           float* __restrict__ Dtab) {
    int t = blockIdx.x * 256 + threadIdx.x;   // 0..1023
    if (t < 128) {
        float c0 = cls[2 * t], c1 = cls[2 * t + 1];
        Dtab[2 * t]     = c0 - c1;
        Dtab[2 * t + 1] = c1;
    }
    int rho = t >> 2, q = t & 3;              // permuted row, k-quad
    int b = rho >> 5, row32 = rho & 31;
    int hb = (row32 >> 2) & 1;
    int r = (row32 & 3) + 4 * (row32 >> 3);
    int node = slot_of(b, hb, r) - 1;
    half8 wv;
    float s = 0.0f;
#pragma unroll
    for (int k0 = 0; k0 < 8; ++k0) {
        int k = 8 * q + k0;
        float w = fi[(node << 5) + k];
        w = w > 0.0f ? w : 0.0f;
        wv[k0] = (_Float16)(w * LOG2E);
        s = fmaf(w, fsig(fs[(node << 5) + k]), s);
    }
    *(half8*)(Wh + (rho << 5) + 8 * q) = wv;
    s += __shfl_xor(s, 1, 64);
    s += __shfl_xor(s, 2, 64);
    if (q == 0) negc[b * 32 + hb * 16 + r] = -s * LOG2E;
}

// Fused: 4 waves/block, 32 samples/wave/tile, 2 tiles/block.
// grid 1024 = co-resident capacity at 4 waves/SIMD -> zero tail.
// A fragments (sample-independent) resident in 64 VGPRs across both tiles.
__global__ __launch_bounds__(256, 4) void dtree_fused(
    const float* __restrict__ x, const _Float16* __restrict__ Wh,
    const float* __restrict__ negc, const float* __restrict__ Dtab,
    float* __restrict__ out)
{
    __shared__ __align__(64) float sNegc[256];   // 1 KB broadcast
    __shared__ __align__(64) float sDtab[256];   // 1 KB broadcast

    const int tid = threadIdx.x;
    const int w = tid >> 6;          // wave in block (0..3)
    const int l = tid & 63;
    const int s32 = l & 31;          // sample col
    const int hb = l >> 5;           // half-wave group

    if (tid < 64)        ((f32x4*)sNegc)[tid]      = ((const f32x4*)negc)[tid];
    else if (tid < 128)  ((f32x4*)sDtab)[tid - 64] = ((const f32x4*)Dtab)[tid - 64];
    __syncthreads();

    // Resident A fragments: 16 x half8 = 64 VGPR, reused for both tiles.
#define LOADA(b) \
    half8 a##b##0 = *(const half8*)(Wh + ((32 * (b) + s32) << 5) + 8 * hb); \
    half8 a##b##1 = *(const half8*)(Wh + ((32 * (b) + s32) << 5) + 16 + 8 * hb);
    LOADA(0) LOADA(1) LOADA(2) LOADA(3) LOADA(4) LOADA(5) LOADA(6) LOADA(7)
#undef LOADA

    const int n0 = blockIdx.x * 128 + w * 32 + s32;
    const int n1 = n0 + (1 << 17);   // + 1024 blocks * 128 samples

    // tile-0 x, convert now; tile-1 x issued early (in flight during tile 0)
    const float* xr0 = x + (size_t)n0 * FDIM;
    f32x4 xa = *(const f32x4*)(xr0 + 8 * hb);
    f32x4 xb = *(const f32x4*)(xr0 + 8 * hb + 4);
    f32x4 xc = *(const f32x4*)(xr0 + 16 + 8 * hb);
    f32x4 xd = *(const f32x4*)(xr0 + 16 + 8 * hb + 4);
    const float* xr1 = x + (size_t)n1 * FDIM;
    f32x4 ya = *(const f32x4*)(xr1 + 8 * hb);
    f32x4 yb = *(const f32x4*)(xr1 + 8 * hb + 4);
    f32x4 yc = *(const f32x4*)(xr1 + 16 + 8 * hb);
    f32x4 yd = *(const f32x4*)(xr1 + 16 + 8 * hb + 4);

#define CVT(bf0, bf1, pa, pb, pc, pd) \
    half8 bf0, bf1; \
    bf0[0]=(_Float16)pa[0]; bf0[1]=(_Float16)pa[1]; bf0[2]=(_Float16)pa[2]; bf0[3]=(_Float16)pa[3]; \
    bf0[4]=(_Float16)pb[0]; bf0[5]=(_Float16)pb[1]; bf0[6]=(_Float16)pb[2]; bf0[7]=(_Float16)pb[3]; \
    bf1[0]=(_Float16)pc[0]; bf1[1]=(_Float16)pc[1]; bf1[2]=(_Float16)pc[2]; bf1[3]=(_Float16)pc[3]; \
    bf1[4]=(_Float16)pd[0]; bf1[5]=(_Float16)pd[1]; bf1[6]=(_Float16)pd[2]; bf1[7]=(_Float16)pd[3];

    // One block b: 2 MFMAs (K=32) -> 16 g -> upward combine of subtree J=8hb+b.
#define BLOCKB(b, BF0, BF1, vout, pgout) do { \
    f32x16 ci_ = *(const f32x16*)(sNegc + (b) * 32 + hb * 16); \
    f32x16 ac_ = __builtin_amdgcn_mfma_f32_32x32x16_f16(a##b##0, BF0, ci_, 0, 0, 0); \
    ac_ = __builtin_amdgcn_mfma_f32_32x32x16_f16(a##b##1, BF1, ac_, 0, 0, 0); \
    const float* dj_ = sDtab + (8 * hb + (b)) * 16; \
    f32x4 dA_ = *(const f32x4*)(dj_); \
    f32x4 dB_ = *(const f32x4*)(dj_ + 4); \
    f32x4 dC_ = *(const f32x4*)(dj_ + 8); \
    f32x4 dD_ = *(const f32x4*)(dj_ + 12); \
    float v70_ = fmaf(fsig2(ac_[0]), dA_[0], dA_[1]); \
    float v71_ = fmaf(fsig2(ac_[1]), dA_[2], dA_[3]); \
    float v72_ = fmaf(fsig2(ac_[2]), dB_[0], dB_[1]); \
    float v73_ = fmaf(fsig2(ac_[3]), dB_[2], dB_[3]); \
    float v74_ = fmaf(fsig2(ac_[4]), dC_[0], dC_[1]); \
    float v75_ = fmaf(fsig2(ac_[5]), dC_[2], dC_[3]); \
    float v76_ = fmaf(fsig2(ac_[6]), dD_[0], dD_[1]); \
    float v77_ = fmaf(fsig2(ac_[7]), dD_[2], dD_[3]); \
    float v60_ = fmaf(fsig2(ac_[8]),  v70_ - v71_, v71_); \
    float v61_ = fmaf(fsig2(ac_[9]),  v72_ - v73_, v73_); \
    float v62_ = fmaf(fsig2(ac_[10]), v74_ - v75_, v75_); \
    float v63_ = fmaf(fsig2(ac_[11]), v76_ - v77_, v77_); \
    float v50_ = fmaf(fsig2(ac_[12]), v60_ - v61_, v61_); \
    float v51_ = fmaf(fsig2(ac_[13]), v62_ - v63_, v63_); \
    vout = fmaf(fsig2(ac_[14]), v50_ - v51_, v51_); \
    pgout = fsig2(ac_[15]); \
} while (0)

#define RUN_TILE(BF0, BF1, N) do { \
    float v0,v1,v2,v3,v4,v5,v6,v7, pg0,pg1,pg2,pg3,pg4,pg5,pg6,pg7; \
    BLOCKB(0, BF0, BF1, v0, pg0); \
    BLOCKB(1, BF0, BF1, v1, pg1); \
    BLOCKB(2, BF0, BF1, v2, pg2); \
    BLOCKB(3, BF0, BF1, v3, pg3); \
    BLOCKB(4, BF0, BF1, v4, pg4); \
    BLOCKB(5, BF0, BF1, v5, pg5); \
    BLOCKB(6, BF0, BF1, v6, pg6); \
    BLOCKB(7, BF0, BF1, v7, pg7); \
    float f0   = hb ? (1.0f - pg0) : pg0; \
    float a01  = f0 * pg1; \
    float a01n = f0 - a01; \
    float t0 = a01  * pg2, t1 = a01  - t0; \
    float t2 = a01n * pg3, t3 = a01n - t2; \
    float p0 = t0 * pg4, p1 = t0 - p0; \
    float p2 = t1 * pg5, p3 = t1 - p2; \
    float p4 = t2 * pg6, p5 = t2 - p4; \
    float p6 = t3 * pg7, p7 = t3 - p6; \
    float facc = p0 * v0; \
    facc = fmaf(p1, v1, facc); \
    facc = fmaf(p2, v2, facc); \
    facc = fmaf(p3, v3, facc); \
    facc = fmaf(p4, v4, facc); \
    facc = fmaf(p5, v5, facc); \
    facc = fmaf(p6, v6, facc); \
    facc = fmaf(p7, v7, facc); \
    facc += __shfl_xor(facc, 32, 64); \
    if (l < 32) out[N] = facc; \
} while (0)

    {
        CVT(bf00, bf01, xa, xb, xc, xd);
        RUN_TILE(bf00, bf01, n0);
    }
    {
        CVT(bf10, bf11, ya, yb, yc, yd);
        RUN_TILE(bf10, bf11, n1);
    }
#undef RUN_TILE
#undef BLOCKB
#undef CVT
}

extern "C" void kernel_launch(void* const* d_in, const int* in_sizes, int n_in,
                              void* d_out, int out_size, void* d_ws, size_t ws_size,
                              hipStream_t stream) {
    const float* x   = (const float*)d_in[0];
    const float* fi  = (const float*)d_in[1];
    const float* fs  = (const float*)d_in[2];
    const float* cls = (const float*)d_in[3];

    _Float16* Wh = (_Float16*)d_ws;                        // 256*32*2 = 16 KB
    float* negc  = (float*)((char*)d_ws + 16384);          // 1 KB
    float* Dtab  = negc + 256;                             // 1 KB

    float* out = (float*)d_out;

    hipLaunchKernelGGL(dtree_prep, dim3(4), dim3(256), 0, stream, fi, fs, cls, Wh, negc, Dtab);
    hipLaunchKernelGGL(dtree_fused, dim3(1024), dim3(256), 0, stream,
                       x, Wh, negc, Dtab, out);
}

// Round 12
// 27.564 us; speedup vs baseline: 7.1870x; 7.1870x over previous
//
#include <hip/hip_runtime.h>

#define FDIM 32
#define LOG2E 1.44269504088896340f

typedef _Float16 half8  __attribute__((ext_vector_type(8)));
typedef float    f32x4  __attribute__((ext_vector_type(4)));
typedef float    f32x16 __attribute__((ext_vector_type(16)));

// base-2 sigmoid: z' = z*log2e pre-scaled; sigma = 1/(1+2^-z')
__device__ __forceinline__ float fsig2(float z2) {
    return __builtin_amdgcn_rcpf(1.0f + __builtin_amdgcn_exp2f(-z2));
}
// true sigmoid (prep only)
__device__ __forceinline__ float fsig(float z) {
    return __builtin_amdgcn_rcpf(1.0f + __builtin_amdgcn_exp2f(-z * LOG2E));
}

// 32x32 MFMA C-layout: col = lane&31 (sample), row32 = (r&3)+8*(r>>2)+4*hb,
// hb = lane>>5, r = C-reg 0..15. Global A-row rho = 32*b + row32 (block b of 8).
// Row permutation: lane (sample, hb), block b, reg r  ->  tree slot so that each
// lane's 16 regs = one complete depth-4 subtree J = 8*hb+b (15 nodes) + 1 path node.
//   r 0..7   -> L7: slot 128+8J+r   (leaf pair t=r)
//   r 8..11  -> L6: slot 64+4J+(r-8)
//   r 12..13 -> L5: slot 32+2J+(r-12)
//   r 14     -> L4: slot 16+J
//   r 15     -> path node: hb=0: {1,2,4,5,8,9,10,11}[b]; hb=1: {1,3,6,7,12,13,14,15}[b]
__device__ __forceinline__ int slot_of(int b, int hb, int r) {
    int J = 8 * hb + b;
    if (r < 8)   return 128 + 8 * J + r;
    if (r < 12)  return 64 + 4 * J + (r - 8);
    if (r < 14)  return 32 + 2 * J + (r - 12);
    if (r == 14) return 16 + J;
    if (b == 0)  return 1;                    // root (duplicated for both hb)
    if (b == 1)  return 2 + hb;
    if (b < 4)   return 4 + 2 * hb + (b - 2);
    return 8 + 4 * hb + (b - 4);
}

// Prep (4 blocks x 256 thr; 4 threads per row, 8 k's each):
// Wh[rho][32] = relu(fi[slot-1])*log2e f16 (permuted), negc[b*32+hb*16+r] =
// -c*log2e, Dtab[16J+2t] = {cls0-cls1, cls1} for leaf pair t of subtree J.
__global__ void dtree_prep(const float* __restrict__ fi, const float* __restrict__ fs,
                           const float* __restrict__ cls,
                           _Float16* __restrict__ Wh, float* __restrict__ negc,
                           float* __restrict__ Dtab) {
    int t = blockIdx.x * 256 + threadIdx.x;   // 0..1023
    if (t < 128) {
        float c0 = cls[2 * t], c1 = cls[2 * t + 1];
        Dtab[2 * t]     = c0 - c1;
        Dtab[2 * t + 1] = c1;
    }
    int rho = t >> 2, q = t & 3;              // permuted row, k-quad
    int b = rho >> 5, row32 = rho & 31;
    int hb = (row32 >> 2) & 1;
    int r = (row32 & 3) + 4 * (row32 >> 3);
    int node = slot_of(b, hb, r) - 1;
    half8 wv;
    float s = 0.0f;
#pragma unroll
    for (int k0 = 0; k0 < 8; ++k0) {
        int k = 8 * q + k0;
        float w = fi[(node << 5) + k];
        w = w > 0.0f ? w : 0.0f;
        wv[k0] = (_Float16)(w * LOG2E);
        s = fmaf(w, fsig(fs[(node << 5) + k]), s);
    }
    *(half8*)(Wh + (rho << 5) + 8 * q) = wv;
    s += __shfl_xor(s, 1, 64);
    s += __shfl_xor(s, 2, 64);
    if (q == 0) negc[b * 32 + hb * 16 + r] = -s * LOG2E;
}

// Fused: 2 fully-independent waves/block (wave-private LDS, no barrier),
// 32 samples/wave via 32x32x16 MFMA pairs. Each lane owns 8 complete subtrees
// + its own 8 path g's -> no cross-lane exchange until final shfl_xor(32).
__global__ __launch_bounds__(128, 6) void dtree_fused(
    const float* __restrict__ x, const _Float16* __restrict__ Wh,
    const float* __restrict__ negc, const float* __restrict__ Dtab,
    float* __restrict__ out)
{
    __shared__ __align__(64) float sNegc[2][256];   // per-wave copies
    __shared__ __align__(64) float sDtab[2][256];

    const int tid = threadIdx.x;
    const int w = tid >> 6;          // wave in block (0/1)
    const int l = tid & 63;
    const int s32 = l & 31;          // sample col
    const int hb = l >> 5;           // half-wave group
    const int n = blockIdx.x * 64 + w * 32 + s32;

    // Wave-private staging (issued first so it's in flight early).
    ((f32x4*)sNegc[w])[l] = ((const f32x4*)negc)[l];
    ((f32x4*)sDtab[w])[l] = ((const f32x4*)Dtab)[l];

    // B fragments: frag0 = x[n][8hb..8hb+7] (k 0..15), frag1 = x[n][16+8hb..]
    const float* xrow = x + (size_t)n * FDIM;
    f32x4 xa = *(const f32x4*)(xrow + 8 * hb);
    f32x4 xb = *(const f32x4*)(xrow + 8 * hb + 4);
    f32x4 xc = *(const f32x4*)(xrow + 16 + 8 * hb);
    f32x4 xd = *(const f32x4*)(xrow + 16 + 8 * hb + 4);
    half8 bf0, bf1;
    bf0[0] = (_Float16)xa[0]; bf0[1] = (_Float16)xa[1];
    bf0[2] = (_Float16)xa[2]; bf0[3] = (_Float16)xa[3];
    bf0[4] = (_Float16)xb[0]; bf0[5] = (_Float16)xb[1];
    bf0[6] = (_Float16)xb[2]; bf0[7] = (_Float16)xb[3];
    bf1[0] = (_Float16)xc[0]; bf1[1] = (_Float16)xc[1];
    bf1[2] = (_Float16)xc[2]; bf1[3] = (_Float16)xc[3];
    bf1[4] = (_Float16)xd[0]; bf1[5] = (_Float16)xd[1];
    bf1[6] = (_Float16)xd[2]; bf1[7] = (_Float16)xd[3];

    // Wave-local producer->consumer through LDS: wave-local wait only.
    asm volatile("s_waitcnt lgkmcnt(0)" ::: "memory");
    __builtin_amdgcn_sched_barrier(0);

    const float* nw = sNegc[w];
    const float* dw = sDtab[w];

    // One block b: 2 MFMAs (K=32) -> 16 g -> upward combine of subtree J=8hb+b.
#define BLOCKB(b, vout, pgout) do { \
    const _Float16* wr_ = Wh + ((32 * (b) + s32) << 5) + 8 * hb; \
    half8 a0_ = *(const half8*)(wr_); \
    half8 a1_ = *(const half8*)(wr_ + 16); \
    f32x16 ci_ = *(const f32x16*)(nw + (b) * 32 + hb * 16); \
    f32x16 ac_ = __builtin_amdgcn_mfma_f32_32x32x16_f16(a0_, bf0, ci_, 0, 0, 0); \
    ac_ = __builtin_amdgcn_mfma_f32_32x32x16_f16(a1_, bf1, ac_, 0, 0, 0); \
    const float* dj_ = dw + (8 * hb + (b)) * 16; \
    f32x4 dA_ = *(const f32x4*)(dj_); \
    f32x4 dB_ = *(const f32x4*)(dj_ + 4); \
    f32x4 dC_ = *(const f32x4*)(dj_ + 8); \
    f32x4 dD_ = *(const f32x4*)(dj_ + 12); \
    float v70_ = fmaf(fsig2(ac_[0]), dA_[0], dA_[1]); \
    float v71_ = fmaf(fsig2(ac_[1]), dA_[2], dA_[3]); \
    float v72_ = fmaf(fsig2(ac_[2]), dB_[0], dB_[1]); \
    float v73_ = fmaf(fsig2(ac_[3]), dB_[2], dB_[3]); \
    float v74_ = fmaf(fsig2(ac_[4]), dC_[0], dC_[1]); \
    float v75_ = fmaf(fsig2(ac_[5]), dC_[2], dC_[3]); \
    float v76_ = fmaf(fsig2(ac_[6]), dD_[0], dD_[1]); \
    float v77_ = fmaf(fsig2(ac_[7]), dD_[2], dD_[3]); \
    float v60_ = fmaf(fsig2(ac_[8]),  v70_ - v71_, v71_); \
    float v61_ = fmaf(fsig2(ac_[9]),  v72_ - v73_, v73_); \
    float v62_ = fmaf(fsig2(ac_[10]), v74_ - v75_, v75_); \
    float v63_ = fmaf(fsig2(ac_[11]), v76_ - v77_, v77_); \
    float v50_ = fmaf(fsig2(ac_[12]), v60_ - v61_, v61_); \
    float v51_ = fmaf(fsig2(ac_[13]), v62_ - v63_, v63_); \
    vout = fmaf(fsig2(ac_[14]), v50_ - v51_, v51_); \
    pgout = fsig2(ac_[15]); \
} while (0)

    float v0, v1, v2, v3, v4, v5, v6, v7;
    float pg0, pg1, pg2, pg3, pg4, pg5, pg6, pg7;
    BLOCKB(0, v0, pg0);
    BLOCKB(1, v1, pg1);
    BLOCKB(2, v2, pg2);
    BLOCKB(3, v3, pg3);
    BLOCKB(4, v4, pg4);
    BLOCKB(5, v5, pg5);
    BLOCKB(6, v6, pg6);
    BLOCKB(7, v7, pg7);
#undef BLOCKB

    // Path prefix products. pg0=root, pg1=slot 2+hb, pg2/3=slots 4/5+2hb,
    // pg4..7=slots 8..11+4hb. Subtree jj=b: bits (jj>>2, jj>>1&1, jj&1).
    float f0   = hb ? (1.0f - pg0) : pg0;
    float a01  = f0 * pg1;
    float a01n = f0 - a01;                    // f0*(1-pg1)
    float t0 = a01  * pg2, t1 = a01  - t0;
    float t2 = a01n * pg3, t3 = a01n - t2;
    float p0 = t0 * pg4, p1 = t0 - p0;
    float p2 = t1 * pg5, p3 = t1 - p2;
    float p4 = t2 * pg6, p5 = t2 - p4;
    float p6 = t3 * pg7, p7 = t3 - p6;

    float facc = p0 * v0;
    facc = fmaf(p1, v1, facc);
    facc = fmaf(p2, v2, facc);
    facc = fmaf(p3, v3, facc);
    facc = fmaf(p4, v4, facc);
    facc = fmaf(p5, v5, facc);
    facc = fmaf(p6, v6, facc);
    facc = fmaf(p7, v7, facc);

    // combine the two hb-halves of each sample
    facc += __shfl_xor(facc, 32, 64);
    if (l < 32) out[n] = facc;
}

extern "C" void kernel_launch(void* const* d_in, const int* in_sizes, int n_in,
                              void* d_out, int out_size, void* d_ws, size_t ws_size,
                              hipStream_t stream) {
    const float* x   = (const float*)d_in[0];
    const float* fi  = (const float*)d_in[1];
    const float* fs  = (const float*)d_in[2];
    const float* cls = (const float*)d_in[3];

    _Float16* Wh = (_Float16*)d_ws;                        // 256*32*2 = 16 KB
    float* negc  = (float*)((char*)d_ws + 16384);          // 1 KB
    float* Dtab  = negc + 256;                             // 1 KB

    int nsamp = in_sizes[0] / FDIM;                        // 262144
    float* out = (float*)d_out;

    hipLaunchKernelGGL(dtree_prep, dim3(4), dim3(256), 0, stream, fi, fs, cls, Wh, negc, Dtab);
    hipLaunchKernelGGL(dtree_fused, dim3(nsamp / 64), dim3(128), 0, stream,
                       x, Wh, negc, Dtab, out);
}